// Round 5
// baseline (195.953 us; speedup 1.0000x reference)
//
#include <hip/hip_runtime.h>

// AdjMlp: out[r, :] = sum over edges (r, c) of weight[c, :]
// v5: fixed-capacity row buckets (CAP=8) built with int atomics; gather does
// 8 rows/wave with 16 unconditional independent 1KB weight loads in flight.
// Invalid slots are handled by clamping the col index to 0 (address-safe)
// and masking the accumulate (value-safe) -> bucket needs NO zero-init;
// memset shrinks to counts+ovf_n (400KB). Overflow rows (deg>CAP, ~never)
// are resolved inside gather by scanning the overflow list (register accum,
// no atomics, no extra dispatch). 3 dispatches total: memset, fill, gather.

constexpr int OUT_F = 256;
constexpr int CAP = 8;          // bucket slots per row
constexpr int MAXOVF = 16384;   // overflow edge capacity

// ---------------- build ----------------

__global__ __launch_bounds__(256) void fill_k(const int* __restrict__ rows,
                                              const int* __restrict__ cols,
                                              int* __restrict__ counts,
                                              int* __restrict__ bucket,
                                              int* __restrict__ ovf_n,
                                              int* __restrict__ ovf,
                                              int nnz) {
    int e = blockIdx.x * 256 + threadIdx.x;
    if (e >= nnz) return;
    int r = rows[e];
    int c = cols[e];
    int slot = atomicAdd(&counts[r], 1);
    if (slot < CAP) {
        bucket[r * CAP + slot] = c;
    } else {
        int o = atomicAdd(ovf_n, 1);
        if (o < MAXOVF) { ovf[2 * o] = r; ovf[2 * o + 1] = c; }
    }
}

// ---------------- gather ----------------

__device__ __forceinline__ void fmacc(float4& a, float m, const float4& v) {
    a.x = fmaf(m, v.x, a.x); a.y = fmaf(m, v.y, a.y);
    a.z = fmaf(m, v.z, a.z); a.w = fmaf(m, v.w, a.w);
}
__device__ __forceinline__ void addacc(float4& a, const float4& v) {
    a.x += v.x; a.y += v.y; a.z += v.z; a.w += v.w;
}

// overflow resolution: scan the (tiny) ovf list for this row, accumulate in regs
__device__ __forceinline__ void ovf_scan(float4& acc, int row,
                                         const int* __restrict__ ovf_n,
                                         const int* __restrict__ ovf,
                                         const float4* __restrict__ w4, int lane) {
    int m = *ovf_n; if (m > MAXOVF) m = MAXOVF;
    for (int j = 0; j < m; j++) {
        if (ovf[2 * j] == row)
            addacc(acc, w4[(size_t)ovf[2 * j + 1] * 64 + lane]);
    }
}

__global__ __launch_bounds__(256) void gather_k(const int* __restrict__ counts,
                                                const int4* __restrict__ bucket4,
                                                const float4* __restrict__ w4,
                                                float4* __restrict__ out4,
                                                const int* __restrict__ ovf_n,
                                                const int* __restrict__ ovf,
                                                int nrows) {
    const int lane = threadIdx.x & 63;
    int wid = (blockIdx.x << 2) + (threadIdx.x >> 6);
    wid = __builtin_amdgcn_readfirstlane(wid);   // wave-uniform -> scalar regs
    const int row0 = wid << 3;                   // 8 rows per wave
    if (row0 >= nrows) return;

    if (row0 + 8 <= nrows) {
        // uniform loads: counts for 8 rows + bucket slots 0..3 for 8 rows
        const int4 cA = *(const int4*)(counts + row0);
        const int4 cB = *(const int4*)(counts + row0 + 4);
        const int n[8] = {cA.x, cA.y, cA.z, cA.w, cB.x, cB.y, cB.z, cB.w};
        int4 b[8];
        #pragma unroll
        for (int i = 0; i < 8; i++) b[i] = bucket4[(size_t)(row0 + i) * 2];

        // 16 unconditional, independent 1KB row loads in flight.
        // Invalid slots: col clamped to 0 (address-safe; row 0 is L2-hot).
        float4 v0[8], v1[8];
        #pragma unroll
        for (int i = 0; i < 8; i++) {
            const int c0 = (n[i] > 0) ? b[i].x : 0;
            v0[i] = w4[(size_t)c0 * 64 + lane];
        }
        #pragma unroll
        for (int i = 0; i < 8; i++) {
            const int c1 = (n[i] > 1) ? b[i].y : 0;
            v1[i] = w4[(size_t)c1 * 64 + lane];
        }

        float4 acc[8];
        #pragma unroll
        for (int i = 0; i < 8; i++) {
            acc[i] = make_float4(0.f, 0.f, 0.f, 0.f);
            fmacc(acc[i], (n[i] > 0) ? 1.f : 0.f, v0[i]);
            fmacc(acc[i], (n[i] > 1) ? 1.f : 0.f, v1[i]);
        }

        // rare tails (P(n>2) ~ 8% per row), wave-uniform branches
        #pragma unroll
        for (int i = 0; i < 8; i++) {
            if (n[i] > 2) {
                addacc(acc[i], w4[(size_t)b[i].z * 64 + lane]);
                if (n[i] > 3) addacc(acc[i], w4[(size_t)b[i].w * 64 + lane]);
                if (n[i] > 4) {
                    const int4 b1 = bucket4[(size_t)(row0 + i) * 2 + 1];
                    const int m = (n[i] < CAP) ? n[i] : CAP;
                    addacc(acc[i], w4[(size_t)b1.x * 64 + lane]);
                    if (m > 5) addacc(acc[i], w4[(size_t)b1.y * 64 + lane]);
                    if (m > 6) addacc(acc[i], w4[(size_t)b1.z * 64 + lane]);
                    if (m > 7) addacc(acc[i], w4[(size_t)b1.w * 64 + lane]);
                    if (n[i] > CAP) ovf_scan(acc[i], row0 + i, ovf_n, ovf, w4, lane);
                }
            }
        }

        // 8KB contiguous store per wave
        #pragma unroll
        for (int i = 0; i < 8; i++)
            out4[(size_t)(row0 + i) * 64 + lane] = acc[i];
    } else {
        for (int r = row0; r < nrows; r++) {
            const int n = counts[r];
            float4 acc = make_float4(0.f, 0.f, 0.f, 0.f);
            if (n > 0) {
                const int4 b0 = bucket4[(size_t)r * 2];
                addacc(acc, w4[(size_t)b0.x * 64 + lane]);
                if (n > 1) addacc(acc, w4[(size_t)b0.y * 64 + lane]);
                if (n > 2) addacc(acc, w4[(size_t)b0.z * 64 + lane]);
                if (n > 3) addacc(acc, w4[(size_t)b0.w * 64 + lane]);
                if (n > 4) {
                    const int4 b1 = bucket4[(size_t)r * 2 + 1];
                    const int m = (n < CAP) ? n : CAP;
                    addacc(acc, w4[(size_t)b1.x * 64 + lane]);
                    if (m > 5) addacc(acc, w4[(size_t)b1.y * 64 + lane]);
                    if (m > 6) addacc(acc, w4[(size_t)b1.z * 64 + lane]);
                    if (m > 7) addacc(acc, w4[(size_t)b1.w * 64 + lane]);
                    if (n > CAP) ovf_scan(acc, r, ovf_n, ovf, w4, lane);
                }
            }
            out4[(size_t)r * 64 + lane] = acc;
        }
    }
}

// ---------------- emergency fallback (no workspace): atomic scatter ----------

__global__ __launch_bounds__(256) void zero_f4(float4* __restrict__ out, int n4) {
    int i = blockIdx.x * 256 + threadIdx.x;
    if (i < n4) out[i] = make_float4(0.f, 0.f, 0.f, 0.f);
}

__global__ __launch_bounds__(256) void scatter_kernel(const int* __restrict__ rows,
                                                      const int* __restrict__ cols,
                                                      const float* __restrict__ weight,
                                                      float* __restrict__ out, int nnz) {
    const int lane = threadIdx.x & 63;
    const int edge = blockIdx.x * 4 + (threadIdx.x >> 6);
    if (edge >= nnz) return;
    const int r = rows[edge];
    const int c = cols[edge];
    const float4 v = ((const float4*)(weight + (size_t)c * OUT_F))[lane];
    float* o = out + (size_t)r * OUT_F + (size_t)lane * 4;
    atomicAdd(o + 0, v.x);
    atomicAdd(o + 1, v.y);
    atomicAdd(o + 2, v.z);
    atomicAdd(o + 3, v.w);
}

// ---------------- launch ----------------

extern "C" void kernel_launch(void* const* d_in, const int* in_sizes, int n_in,
                              void* d_out, int out_size, void* d_ws, size_t ws_size,
                              hipStream_t stream) {
    const int* adj = (const int*)d_in[0];          // [2, nnz] int32
    const int nnz = in_sizes[0] / 2;
    const int* rows = adj;
    const int* cols = adj + nnz;
    const float* weight = (const float*)d_in[2];   // [IN_F, 256] fp32
    float* out = (float*)d_out;                    // [nrows, 256] fp32
    const int nrows = out_size / OUT_F;

    // workspace (ints): counts[nrows] | ovf_n[4] | ovf[2*MAXOVF] | bucket[nrows*CAP]
    // (counts..ovf_n is the only region that needs zeroing: 400KB + 16B)
    const size_t ovfnOff   = (size_t)nrows;                  // 16B-aligned (nrows%4==0)
    const size_t ovfOff    = ovfnOff + 4;
    const size_t bucketOff = ovfOff + 2 * MAXOVF;            // stays 16B-aligned
    const size_t need      = (bucketOff + (size_t)nrows * CAP) * 4;

    if (ws_size >= need && (nrows & 7) == 0) {
        int* wsI    = (int*)d_ws;
        int* counts = wsI;
        int* ovf_n  = wsI + ovfnOff;
        int* ovf    = wsI + ovfOff;
        int* bucket = wsI + bucketOff;

        hipMemsetAsync(counts, 0, (ovfOff) * 4, stream);     // counts + ovf_n only
        fill_k<<<(nnz + 255) / 256, 256, 0, stream>>>(rows, cols, counts, bucket,
                                                      ovf_n, ovf, nnz);
        const int waves = (nrows + 7) / 8;
        gather_k<<<(waves + 3) / 4, 256, 0, stream>>>(counts, (const int4*)bucket,
                                                      (const float4*)weight,
                                                      (float4*)out, ovf_n, ovf, nrows);
    } else {
        // no usable workspace / odd shape: zero + atomic scatter (correct, slower)
        const int n4 = out_size / 4;
        zero_f4<<<(n4 + 255) / 256, 256, 0, stream>>>((float4*)out, n4);
        scatter_kernel<<<(nnz + 3) / 4, 256, 0, stream>>>(rows, cols, weight, out, nnz);
    }
}

// Round 6
// 193.339 us; speedup vs baseline: 1.0135x; 1.0135x over previous
//
#include <hip/hip_runtime.h>

// AdjMlp: out[r, :] = sum over edges (r, c) of weight[c, :]
// v6 = best of v4+v5: fixed-capacity row buckets (CAP=8); gather processes
// 4 rows/wave (8 independent weight loads in flight, ~85 VGPRs -> ~6 waves/SIMD
// occupancy; v5's 8-rows/wave cost more occupancy than its MLP gained).
// Invalid slots: col clamped to 0 (address-safe) + masked fmac (value-safe)
// -> no bucket zero-init; memset is counts+ovf_n only (400KB).
// Overflow rows (deg>CAP) resolved inside gather by scanning ovf list.
// Nontemporal: out stores + counts/bucket loads (single-use) keep L2 for weight.
// 3 dispatches: memset, fill, gather.

constexpr int OUT_F = 256;
constexpr int CAP = 8;          // bucket slots per row
constexpr int MAXOVF = 16384;   // overflow edge capacity

using f32x4 = __attribute__((ext_vector_type(4))) float;
using i32x4 = __attribute__((ext_vector_type(4))) int;

// ---------------- build ----------------

__global__ __launch_bounds__(256) void fill_k(const int* __restrict__ rows,
                                              const int* __restrict__ cols,
                                              int* __restrict__ counts,
                                              int* __restrict__ bucket,
                                              int* __restrict__ ovf_n,
                                              int* __restrict__ ovf,
                                              int nnz) {
    int e = blockIdx.x * 256 + threadIdx.x;
    if (e >= nnz) return;
    int r = rows[e];
    int c = cols[e];
    int slot = atomicAdd(&counts[r], 1);
    if (slot < CAP) {
        bucket[r * CAP + slot] = c;
    } else {
        int o = atomicAdd(ovf_n, 1);
        if (o < MAXOVF) { ovf[2 * o] = r; ovf[2 * o + 1] = c; }
    }
}

// ---------------- gather ----------------

// overflow resolution: scan the (tiny) ovf list for this row, accumulate in regs
__device__ __forceinline__ void ovf_scan(f32x4& acc, int row,
                                         const int* __restrict__ ovf_n,
                                         const int* __restrict__ ovf,
                                         const f32x4* __restrict__ w4, int lane) {
    int m = *ovf_n; if (m > MAXOVF) m = MAXOVF;
    for (int j = 0; j < m; j++) {
        if (ovf[2 * j] == row)
            acc += w4[(size_t)ovf[2 * j + 1] * 64 + lane];
    }
}

// slots 2..min(n,CAP)-1 + overflow; called only when n > 2 (wave-uniform, ~8%)
__device__ __forceinline__ void rare_tail(f32x4& acc, int n, const i32x4& b0,
                                          const i32x4* __restrict__ bucket4, int row,
                                          const f32x4* __restrict__ w4, int lane,
                                          const int* __restrict__ ovf_n,
                                          const int* __restrict__ ovf) {
    int m = n < CAP ? n : CAP;
    acc += w4[(size_t)b0.z * 64 + lane];
    if (m > 3) acc += w4[(size_t)b0.w * 64 + lane];
    if (m > 4) {
        i32x4 b1 = __builtin_nontemporal_load(bucket4 + (size_t)row * 2 + 1);
        acc += w4[(size_t)b1.x * 64 + lane];
        if (m > 5) acc += w4[(size_t)b1.y * 64 + lane];
        if (m > 6) acc += w4[(size_t)b1.z * 64 + lane];
        if (m > 7) acc += w4[(size_t)b1.w * 64 + lane];
        if (n > CAP) ovf_scan(acc, row, ovf_n, ovf, w4, lane);
    }
}

__global__ __launch_bounds__(256) void gather_k(const int* __restrict__ counts,
                                                const i32x4* __restrict__ bucket4,
                                                const f32x4* __restrict__ w4,
                                                f32x4* __restrict__ out4,
                                                const int* __restrict__ ovf_n,
                                                const int* __restrict__ ovf,
                                                int nrows) {
    const int lane = threadIdx.x & 63;
    int wid = (blockIdx.x << 2) + (threadIdx.x >> 6);
    wid = __builtin_amdgcn_readfirstlane(wid);   // wave-uniform -> scalar regs
    const int row0 = wid << 2;                   // 4 rows per wave
    if (row0 >= nrows) return;

    if (row0 + 4 <= nrows) {
        // single-use metadata: nontemporal (don't pollute L2; keep it for weight)
        const i32x4 cnt = __builtin_nontemporal_load((const i32x4*)(counts + row0));
        const i32x4 ba = __builtin_nontemporal_load(bucket4 + (size_t)(row0 + 0) * 2);
        const i32x4 bb = __builtin_nontemporal_load(bucket4 + (size_t)(row0 + 1) * 2);
        const i32x4 bc = __builtin_nontemporal_load(bucket4 + (size_t)(row0 + 2) * 2);
        const i32x4 bd = __builtin_nontemporal_load(bucket4 + (size_t)(row0 + 3) * 2);

        // 8 unconditional, independent 1KB row loads in flight.
        // Invalid slots: col clamped to 0 (address-safe; row 0 stays L2-hot).
        const f32x4 va0 = w4[(size_t)(cnt.x > 0 ? ba.x : 0) * 64 + lane];
        const f32x4 va1 = w4[(size_t)(cnt.x > 1 ? ba.y : 0) * 64 + lane];
        const f32x4 vb0 = w4[(size_t)(cnt.y > 0 ? bb.x : 0) * 64 + lane];
        const f32x4 vb1 = w4[(size_t)(cnt.y > 1 ? bb.y : 0) * 64 + lane];
        const f32x4 vc0 = w4[(size_t)(cnt.z > 0 ? bc.x : 0) * 64 + lane];
        const f32x4 vc1 = w4[(size_t)(cnt.z > 1 ? bc.y : 0) * 64 + lane];
        const f32x4 vd0 = w4[(size_t)(cnt.w > 0 ? bd.x : 0) * 64 + lane];
        const f32x4 vd1 = w4[(size_t)(cnt.w > 1 ? bd.y : 0) * 64 + lane];

        f32x4 a0 = {0.f, 0.f, 0.f, 0.f};
        f32x4 a1 = a0, a2 = a0, a3 = a0;
        a0 += (cnt.x > 0 ? 1.f : 0.f) * va0;
        a0 += (cnt.x > 1 ? 1.f : 0.f) * va1;
        a1 += (cnt.y > 0 ? 1.f : 0.f) * vb0;
        a1 += (cnt.y > 1 ? 1.f : 0.f) * vb1;
        a2 += (cnt.z > 0 ? 1.f : 0.f) * vc0;
        a2 += (cnt.z > 1 ? 1.f : 0.f) * vc1;
        a3 += (cnt.w > 0 ? 1.f : 0.f) * vd0;
        a3 += (cnt.w > 1 ? 1.f : 0.f) * vd1;

        if (cnt.x > 2) rare_tail(a0, cnt.x, ba, bucket4, row0 + 0, w4, lane, ovf_n, ovf);
        if (cnt.y > 2) rare_tail(a1, cnt.y, bb, bucket4, row0 + 1, w4, lane, ovf_n, ovf);
        if (cnt.z > 2) rare_tail(a2, cnt.z, bc, bucket4, row0 + 2, w4, lane, ovf_n, ovf);
        if (cnt.w > 2) rare_tail(a3, cnt.w, bd, bucket4, row0 + 3, w4, lane, ovf_n, ovf);

        // 4KB contiguous nontemporal store per wave (write-once stream)
        __builtin_nontemporal_store(a0, out4 + (size_t)(row0 + 0) * 64 + lane);
        __builtin_nontemporal_store(a1, out4 + (size_t)(row0 + 1) * 64 + lane);
        __builtin_nontemporal_store(a2, out4 + (size_t)(row0 + 2) * 64 + lane);
        __builtin_nontemporal_store(a3, out4 + (size_t)(row0 + 3) * 64 + lane);
    } else {
        for (int r = row0; r < nrows; r++) {
            const int n = counts[r];
            f32x4 acc = {0.f, 0.f, 0.f, 0.f};
            if (n > 0) {
                const i32x4 b0 = bucket4[(size_t)r * 2];
                acc += w4[(size_t)b0.x * 64 + lane];
                if (n > 1) acc += w4[(size_t)b0.y * 64 + lane];
                if (n > 2) rare_tail(acc, n, b0, bucket4, r, w4, lane, ovf_n, ovf);
            }
            __builtin_nontemporal_store(acc, out4 + (size_t)r * 64 + lane);
        }
    }
}

// ---------------- emergency fallback (no workspace): atomic scatter ----------

__global__ __launch_bounds__(256) void zero_f4(float4* __restrict__ out, int n4) {
    int i = blockIdx.x * 256 + threadIdx.x;
    if (i < n4) out[i] = make_float4(0.f, 0.f, 0.f, 0.f);
}

__global__ __launch_bounds__(256) void scatter_kernel(const int* __restrict__ rows,
                                                      const int* __restrict__ cols,
                                                      const float* __restrict__ weight,
                                                      float* __restrict__ out, int nnz) {
    const int lane = threadIdx.x & 63;
    const int edge = blockIdx.x * 4 + (threadIdx.x >> 6);
    if (edge >= nnz) return;
    const int r = rows[edge];
    const int c = cols[edge];
    const float4 v = ((const float4*)(weight + (size_t)c * OUT_F))[lane];
    float* o = out + (size_t)r * OUT_F + (size_t)lane * 4;
    atomicAdd(o + 0, v.x);
    atomicAdd(o + 1, v.y);
    atomicAdd(o + 2, v.z);
    atomicAdd(o + 3, v.w);
}

// ---------------- launch ----------------

extern "C" void kernel_launch(void* const* d_in, const int* in_sizes, int n_in,
                              void* d_out, int out_size, void* d_ws, size_t ws_size,
                              hipStream_t stream) {
    const int* adj = (const int*)d_in[0];          // [2, nnz] int32
    const int nnz = in_sizes[0] / 2;
    const int* rows = adj;
    const int* cols = adj + nnz;
    const float* weight = (const float*)d_in[2];   // [IN_F, 256] fp32
    float* out = (float*)d_out;                    // [nrows, 256] fp32
    const int nrows = out_size / OUT_F;

    // workspace (ints): counts[nrows] | ovf_n[4] | ovf[2*MAXOVF] | bucket[nrows*CAP]
    // only counts+ovf_n need zeroing (400KB + 16B)
    const size_t ovfnOff   = (size_t)nrows;                  // 16B-aligned (nrows%4==0)
    const size_t ovfOff    = ovfnOff + 4;
    const size_t bucketOff = ovfOff + 2 * MAXOVF;            // stays 16B-aligned
    const size_t need      = (bucketOff + (size_t)nrows * CAP) * 4;

    if (ws_size >= need && (nrows & 3) == 0) {
        int* wsI    = (int*)d_ws;
        int* counts = wsI;
        int* ovf_n  = wsI + ovfnOff;
        int* ovf    = wsI + ovfOff;
        int* bucket = wsI + bucketOff;

        hipMemsetAsync(counts, 0, ovfOff * 4, stream);       // counts + ovf_n only
        fill_k<<<(nnz + 255) / 256, 256, 0, stream>>>(rows, cols, counts, bucket,
                                                      ovf_n, ovf, nnz);
        gather_k<<<(nrows + 15) / 16, 256, 0, stream>>>(counts, (const i32x4*)bucket,
                                                        (const f32x4*)weight,
                                                        (f32x4*)out, ovf_n, ovf, nrows);
    } else {
        // no usable workspace / odd shape: zero + atomic scatter (correct, slower)
        const int n4 = out_size / 4;
        zero_f4<<<(n4 + 255) / 256, 256, 0, stream>>>((float4*)out, n4);
        scatter_kernel<<<(nnz + 3) / 4, 256, 0, stream>>>(rows, cols, weight, out, nnz);
    }
}